// Round 1
// baseline (102.972 us; speedup 1.0000x reference)
//
#include <hip/hip_runtime.h>
#include <math.h>

// Problem constants (from reference)
#define NS 100000
#define H 128
#define NHEADS 4
#define NPAIRS (NS / 2)   // rows processed 2 per wave (32 lanes per row)
#define TPB 256
#define NBLK 1024
#define NREP 8            // replicated accumulators to cut atomic contention
// ws layout: float g[NREP][258]  -> [0..127]=u_plus, [128..255]=u_minus, [256]=S+, [257]=S-

__device__ __forceinline__ float half_reduce(float v) {
    // butterfly sum within each 32-lane half of the wave64
    v += __shfl_xor(v, 1);
    v += __shfl_xor(v, 2);
    v += __shfl_xor(v, 4);
    v += __shfl_xor(v, 8);
    v += __shfl_xor(v, 16);
    return v;
}

__global__ __launch_bounds__(TPB) void fp_pass1(const float* __restrict__ e,
                                                const float* __restrict__ q,
                                                float* __restrict__ g) {
    const int tid  = threadIdx.x;
    const int lane = tid & 63;
    const int widx = tid >> 6;        // wave index within block (0..3)
    const int half = lane >> 5;       // 0 or 1: which row of the pair
    const int c4   = (lane & 31) << 2;  // column base: 32 lanes x 4 floats = 128 cols

    // q fragment + ||q||
    const float4 q4 = *(const float4*)(q + c4);
    float qnsq = q4.x * q4.x + q4.y * q4.y + q4.z * q4.z + q4.w * q4.w;
    qnsq = half_reduce(qnsq);
    const float inv_qn = rsqrtf(qnsq);

    float4 up = {0.f, 0.f, 0.f, 0.f};
    float4 um = {0.f, 0.f, 0.f, 0.f};
    float sp = 0.f, sm = 0.f;

    const int gw = blockIdx.x * (TPB / 64) + widx;  // global wave id
    const int W  = NBLK * (TPB / 64);               // total waves

    // Each trip: the wave reads rows 2p and 2p+1 -> one fully-coalesced 1KB load.
#pragma unroll 2
    for (int p = gw; p < NPAIRS; p += W) {
        const int row = 2 * p + half;
        const float4 ev = *(const float4*)(e + (size_t)row * H + c4);
        float d  = ev.x * q4.x + ev.y * q4.y + ev.z * q4.z + ev.w * q4.w;
        float ns = ev.x * ev.x + ev.y * ev.y + ev.z * ev.z + ev.w * ev.w;
        d  = half_reduce(d);
        ns = half_reduce(ns);
        const float c  = d * rsqrtf(ns) * inv_qn;   // cos(q, e_row), uniform in half
        const float wp = fmaxf(c, 0.f);
        const float wm = fmaxf(-c, 0.f);
        sp += wp;
        sm += wm;
        up.x = fmaf(wp, ev.x, up.x); up.y = fmaf(wp, ev.y, up.y);
        up.z = fmaf(wp, ev.z, up.z); up.w = fmaf(wp, ev.w, up.w);
        um.x = fmaf(wm, ev.x, um.x); um.y = fmaf(wm, ev.y, um.y);
        um.z = fmaf(wm, ev.z, um.z); um.w = fmaf(wm, ev.w, um.w);
    }

    // Block-level reduction in LDS: 8 half-slots (4 waves x 2 halves)
    __shared__ float s_up[8][H];
    __shared__ float s_um[8][H];
    __shared__ float s_s[8][2];
    const int hs = widx * 2 + half;
    *(float4*)(&s_up[hs][c4]) = up;
    *(float4*)(&s_um[hs][c4]) = um;
    if ((lane & 31) == 0) {  // sp/sm identical across the half after butterfly
        s_s[hs][0] = sp;
        s_s[hs][1] = sm;
    }
    __syncthreads();

    float* gr = g + (blockIdx.x & (NREP - 1)) * 258;
    if (tid < H) {
        float a = 0.f;
#pragma unroll
        for (int h2 = 0; h2 < 8; ++h2) a += s_up[h2][tid];
        atomicAdd(&gr[tid], a);
    } else {
        const int t = tid - H;
        float a = 0.f;
#pragma unroll
        for (int h2 = 0; h2 < 8; ++h2) a += s_um[h2][t];
        atomicAdd(&gr[H + t], a);
    }
    if (tid < 2) {
        float a = 0.f;
#pragma unroll
        for (int h2 = 0; h2 < 8; ++h2) a += s_s[h2][tid];
        atomicAdd(&gr[256 + tid], a);
    }
}

__global__ __launch_bounds__(256) void fp_finalize(const float* __restrict__ g,
                                                   const float* __restrict__ w_key,
                                                   const float* __restrict__ w_value,
                                                   const float* __restrict__ mu_w,
                                                   const float* __restrict__ mu_b,
                                                   const float* __restrict__ sigma_w,
                                                   const float* __restrict__ sigma_b,
                                                   float* __restrict__ out) {
    __shared__ float tot[258];
    const int tid = threadIdx.x;  // 256 threads
    {
        float a = 0.f;
#pragma unroll
        for (int r = 0; r < NREP; ++r) a += g[r * 258 + tid];
        tot[tid] = a;
    }
    if (tid < 2) {
        float a = 0.f;
#pragma unroll
        for (int r = 0; r < NREP; ++r) a += g[r * 258 + 256 + tid];
        tot[256 + tid] = a;
    }
    __syncthreads();

    if (tid < 64) {
        const int l = tid;
        const float up0 = tot[2 * l], up1 = tot[2 * l + 1];
        const float um0 = tot[H + 2 * l], um1 = tot[H + 2 * l + 1];
        const float mw0 = mu_w[2 * l], mw1 = mu_w[2 * l + 1];
        const float sw0 = sigma_w[2 * l], sw1 = sigma_w[2 * l + 1];
        float A = up0 * mw0 + up1 * mw1;  // u+ . mu_w
        float B = up0 * sw0 + up1 * sw1;  // u+ . sigma_w
        float C = um0 * mw0 + um1 * mw1;  // u- . mu_w
        float D = um0 * sw0 + um1 * sw1;  // u- . sigma_w
#pragma unroll
        for (int m = 1; m < 64; m <<= 1) {
            A += __shfl_xor(A, m);
            B += __shfl_xor(B, m);
            C += __shfl_xor(C, m);
            D += __shfl_xor(D, m);
        }
        if (l < NHEADS) {
            const float spv = fmaxf(tot[256], 1e-6f);
            const float smv = fmaxf(tot[257], 1e-6f);
            const float wk = w_key[l];
            const float wv = w_value[l];
            float dmu, dsg;
            if (wk > 0.f) {
                dmu = A / spv; dsg = B / spv;
            } else if (wk < 0.f) {
                dmu = C / smv; dsg = D / smv;
            } else {
                dmu = 0.f; dsg = 0.f;
            }
            out[l] = fmaf(wv, dmu, mu_b[0]);
            const float x = fmaf(wv, dsg, sigma_b[0]);
            // numerically-stable softplus
            out[NHEADS + l] = fmaxf(x, 0.f) + log1pf(expf(-fabsf(x)));
        }
    }
}

extern "C" void kernel_launch(void* const* d_in, const int* in_sizes, int n_in,
                              void* d_out, int out_size, void* d_ws, size_t ws_size,
                              hipStream_t stream) {
    const float* e       = (const float*)d_in[0];
    const float* w_key   = (const float*)d_in[1];
    const float* w_value = (const float*)d_in[2];
    const float* q       = (const float*)d_in[3];
    const float* mu_w    = (const float*)d_in[4];
    const float* mu_b    = (const float*)d_in[5];
    const float* sigma_w = (const float*)d_in[6];
    const float* sigma_b = (const float*)d_in[7];
    float* out = (float*)d_out;
    float* g   = (float*)d_ws;

    // ws is re-poisoned to 0xAA before every timed launch -> zero our accumulators.
    hipMemsetAsync(g, 0, (size_t)NREP * 258 * sizeof(float), stream);
    hipLaunchKernelGGL(fp_pass1, dim3(NBLK), dim3(TPB), 0, stream, e, q, g);
    hipLaunchKernelGGL(fp_finalize, dim3(1), dim3(256), 0, stream, g,
                       w_key, w_value, mu_w, mu_b, sigma_w, sigma_b, out);
}